// Round 10
// baseline (44.412 us; speedup 1.0000x reference)
//
#include <hip/hip_runtime.h>

#define A_N 192
#define D_N 576
#define W_N 384
#define NPIX (W_N * W_N)   // 147456
#define NSIN (A_N * D_N)   // 110592
#define RSTR 580           // padded inter row stride (floats)

// ---- K1: heterogeneous grid -----------------------------------------------
// blocks 0..431   : fused conv1+conv2 (collapsed 9x9 class kernels) ->
//                   sino_pred + guard-padded pred-only inter + tab (block 0)
// blocks 432..2735: bpA = backprojection of RAW sino (independent of conv9),
//                   masked taps, per-block LDS angle table. part planes 0..3.
__global__ __launch_bounds__(256) void k1_kernel(
    const float* __restrict__ sino, const float* __restrict__ angles,
    const float* __restrict__ w1, const float* __restrict__ b1,
    const float* __restrict__ w2, const float* __restrict__ b2,
    float* __restrict__ sino_pred, float* __restrict__ inter,
    float4* __restrict__ tab, float* __restrict__ part)
{
    int tid = threadIdx.x;
    if (blockIdx.x < 432) {
        // ------------------ conv9 ------------------
        __shared__ float t[16][40];            // zero-padded 8x32 tile + halo
        __shared__ float sw1[400], sw2[400], sb1[16];
        __shared__ float K[625], wsb1[25];
        __shared__ float Wcs[9][81];
        __shared__ float biasc[9];

        int byi = blockIdx.x / 18;
        int bxi = blockIdx.x % 18;
        int y0 = byi * 8, x0 = bxi * 32;

        if (blockIdx.x == 0) {                 // tab + inter guard cells
            if (tid < A_N) {
                float s, c;
                sincosf(angles[tid], &s, &c);
                tab[tid] = make_float4(c, s, fmaf(576.f, c, -287.5f * s),
                                             fmaf(576.f, s,  287.5f * c));
            }
            for (int i = tid; i < A_N * 4; i += 256) {
                int a = i >> 2, j = i & 3;
                inter[a * RSTR + (j < 2 ? j : 576 + j)] = 0.f;
            }
        }

        for (int i = tid; i < 640; i += 256) {
            int r = i / 40, c = i - r * 40;
            int gy = y0 - 4 + r, gx = x0 - 4 + c;
            t[r][c] = (gy >= 0 && gy < A_N && gx >= 0 && gx < D_N)
                    ? sino[gy * D_N + gx] : 0.f;
        }
        for (int i = tid; i < 400; i += 256) { sw1[i] = w1[i]; sw2[i] = w2[i]; }
        if (tid < 16) sb1[tid] = b1[tid];
        __syncthreads();

        for (int i = tid; i < 625; i += 256) {
            int q = i / 25, r = i - q * 25;
            float acc = 0.f;
            #pragma unroll
            for (int c = 0; c < 16; ++c)
                acc = fmaf(sw2[c * 25 + q], sw1[c * 25 + r], acc);
            K[i] = acc;
        }
        if (tid < 25) {
            float acc = 0.f;
            #pragma unroll
            for (int c = 0; c < 16; ++c)
                acc = fmaf(sw2[c * 25 + tid], sb1[c], acc);
            wsb1[tid] = acc;
        }
        __syncthreads();

        int ylo = (y0 == 0) ? 0 : 2, yhi = (y0 == A_N - 8) ? 4 : 2;
        int xlo = (x0 == 0) ? 0 : 2, xhi = (x0 == D_N - 32) ? 4 : 2;
        int nx = xhi - xlo + 1;
        int nc = (yhi - ylo + 1) * nx;

        for (int e = tid; e < nc * 81; e += 256) {
            int ci = e / 81, s = e - ci * 81;
            int yc = ylo + ci / nx, xc = xlo + ci % nx;
            int sy = s / 9 - 4, sx = s % 9 - 4;
            float acc = 0.f;
            for (int qy = -2; qy <= 2; ++qy) {
                if ((yc == 0 && qy < 0) || (yc == 1 && qy < -1) ||
                    (yc == 3 && qy > 1) || (yc == 4 && qy > 0)) continue;
                int vy = sy - qy; if (vy < -2 || vy > 2) continue;
                for (int qx = -2; qx <= 2; ++qx) {
                    if ((xc == 0 && qx < 0) || (xc == 1 && qx < -1) ||
                        (xc == 3 && qx > 1) || (xc == 4 && qx > 0)) continue;
                    int vx = sx - qx; if (vx < -2 || vx > 2) continue;
                    acc += K[((qy + 2) * 5 + qx + 2) * 25 + (vy + 2) * 5 + (vx + 2)];
                }
            }
            Wcs[ci][s] = acc;
        }
        if (tid < nc) {
            int yc = ylo + tid / nx, xc = xlo + tid % nx;
            float acc = b2[0];
            for (int qy = -2; qy <= 2; ++qy) {
                if ((yc == 0 && qy < 0) || (yc == 1 && qy < -1) ||
                    (yc == 3 && qy > 1) || (yc == 4 && qy > 0)) continue;
                for (int qx = -2; qx <= 2; ++qx) {
                    if ((xc == 0 && qx < 0) || (xc == 1 && qx < -1) ||
                        (xc == 3 && qx > 1) || (xc == 4 && qx > 0)) continue;
                    acc += wsb1[(qy + 2) * 5 + qx + 2];
                }
            }
            biasc[tid] = acc;
        }
        __syncthreads();

        int lr = tid >> 5, lc = tid & 31;
        int gy = y0 + lr, gx = x0 + lc;
        int yc = (gy <= 1) ? gy : ((gy >= A_N - 2) ? (gy - (A_N - 5)) : 2);
        int xc = (gx <= 1) ? gx : ((gx >= D_N - 2) ? (gx - (D_N - 5)) : 2);
        int ci = (yc - ylo) * nx + (xc - xlo);
        float acc = biasc[ci];
        const float* Wp = Wcs[ci];
        #pragma unroll
        for (int sy = 0; sy < 9; ++sy)
            #pragma unroll
            for (int sx = 0; sx < 9; ++sx)
                acc = fmaf(t[lr + sy][lc + sx], Wp[sy * 9 + sx], acc);
        sino_pred[gy * D_N + gx] = acc;
        inter[gy * RSTR + 2 + gx] = acc;
    } else {
        // ------------------ bpA: backproject raw sino ------------------
        __shared__ float4 tl[48];
        int b = blockIdx.x - 432;
        int seg = b / 576;                 // 0..3
        int r   = b % 576;                 // 24x24 tiles
        int a0  = seg * 48;
        if (tid < 48) {
            float s, c;
            sincosf(angles[a0 + tid], &s, &c);
            tl[tid] = make_float4(c, s, fmaf(576.f, c, -287.5f * s),
                                        fmaf(576.f, s,  287.5f * c));
        }
        __syncthreads();
        int gx = (r % 24) * 16 + (tid & 15);
        int gy = (r / 24) * 16 + (tid >> 4);
        float X = (float)gx - 191.5f;
        float Y = (float)gy - 191.5f;
        float acc = 0.f;
        #pragma unroll 4
        for (int i = 0; i < 48; ++i) {
            float4 tb = tl[i];
            float den = fmaf(tb.x, Y, fmaf(-tb.y, X, 576.f));
            float num = fmaf(tb.z, X, fmaf(tb.w, Y, 165600.f));
            float s   = num * __builtin_amdgcn_rcpf(den);
            float fl  = floorf(s);
            float fr  = s - fl;
            int i0 = (int)fl, i1 = i0 + 1;
            float w0 = ((unsigned)i0 < 576u) ? (1.f - fr) : 0.f;
            float w1 = ((unsigned)i1 < 576u) ? fr : 0.f;
            int i0c = min(max(i0, 0), 575);
            int i1c = min(max(i1, 0), 575);
            const float* row = sino + (a0 + i) * D_N;
            acc = fmaf(row[i0c], w0, fmaf(row[i1c], w1, acc));
        }
        part[seg * NPIX + gy * W_N + gx] = acc;
    }
}

// ---- K2: bpB = backproject sino_pred from guard-padded inter ---------------
// fr in [0,1) always; guard zeros at d=-2,-1,576,577 + ic=clamp(i0,-2,576)
// -> branch-free, mask-free. float2 gather covers both taps.
__global__ __launch_bounds__(256) void bpb_kernel(
    const float* __restrict__ inter, const float4* __restrict__ tab,
    float* __restrict__ part)
{
    int tid = threadIdx.x;
    int seg = blockIdx.z;                  // 0..3
    int a0 = seg * 48;
    int gx = blockIdx.x * 16 + (tid & 15);
    int gy = blockIdx.y * 16 + (tid >> 4);
    float X = (float)gx - 191.5f;
    float Y = (float)gy - 191.5f;
    float acc = 0.f;
    const float* base = inter + (size_t)a0 * RSTR + 2;
    #pragma unroll 4
    for (int i = 0; i < 48; ++i) {
        float4 tb = tab[a0 + i];           // uniform -> scalar loads
        float den = fmaf(tb.x, Y, fmaf(-tb.y, X, 576.f));
        float num = fmaf(tb.z, X, fmaf(tb.w, Y, 165600.f));
        float s   = num * __builtin_amdgcn_rcpf(den);
        float fl  = floorf(s);
        float fr  = s - fl;
        int   ic  = min(max((int)fl, -2), 576);
        float2 v = *reinterpret_cast<const float2*>(base + (size_t)i * RSTR + ic);
        acc = fmaf(v.x, 1.f - fr, fmaf(v.y, fr, acc));
    }
    part[(4 + seg) * NPIX + gy * W_N + gx] = acc;
}

// ---- K3: fused partial-sum (x4) + conv3 ------------------------------------
__global__ __launch_bounds__(256) void conv3_kernel(
    const float* __restrict__ part,
    const float* __restrict__ w3, const float* __restrict__ b3,
    float* __restrict__ img_sino, float* __restrict__ img_pred)
{
    __shared__ float t0[10][34], t1[10][34];
    __shared__ float sw[18];
    int tid = threadIdx.x;
    int byi = blockIdx.x / 12, bxi = blockIdx.x % 12;
    int y0 = byi * 8, x0 = bxi * 32;
    for (int i = tid; i < 340; i += 256) {
        int r = i / 34, c = i - r * 34;
        int gy = y0 - 1 + r, gx = x0 - 1 + c;
        float s0 = 0.f, s1 = 0.f;
        if (gy >= 0 && gy < W_N && gx >= 0 && gx < W_N) {
            int g = gy * W_N + gx;
            #pragma unroll
            for (int p = 0; p < 4; ++p) s0 += part[p * NPIX + g];
            #pragma unroll
            for (int p = 4; p < 8; ++p) s1 += part[p * NPIX + g];
        }
        t0[r][c] = s0; t1[r][c] = s1;
    }
    if (tid < 18) sw[tid] = w3[tid];
    __syncthreads();
    int lr = tid >> 5, lc = tid & 31;
    int gy = y0 + lr, gx = x0 + lc;
    int g = gy * W_N + gx;
    img_sino[g] = t1[lr + 1][lc + 1];
    float acc = b3[0];
    #pragma unroll
    for (int dy = 0; dy < 3; ++dy)
        #pragma unroll
        for (int dx = 0; dx < 3; ++dx) {
            acc = fmaf(t0[lr + dy][lc + dx], sw[dy * 3 + dx], acc);
            acc = fmaf(t1[lr + dy][lc + dx], sw[9 + dy * 3 + dx], acc);
        }
    img_pred[g] = acc;
}

extern "C" void kernel_launch(void* const* d_in, const int* in_sizes, int n_in,
                              void* d_out, int out_size, void* d_ws, size_t ws_size,
                              hipStream_t stream) {
    const float* sino   = (const float*)d_in[0];
    const float* angles = (const float*)d_in[1];
    const float* w1     = (const float*)d_in[2];
    const float* b1     = (const float*)d_in[3];
    const float* w2     = (const float*)d_in[4];
    const float* b2     = (const float*)d_in[5];
    const float* w3     = (const float*)d_in[6];
    const float* b3     = (const float*)d_in[7];

    float* out       = (float*)d_out;
    float* sino_pred = out;                       // 110592
    float* img_sino  = out + NSIN;                // 147456
    float* img_pred  = img_sino + NPIX;           // 147456

    float*  inter = (float*)d_ws;                               // 192*580
    float4* tab   = (float4*)((char*)d_ws + (size_t)A_N * RSTR * 4);
    float*  part  = (float*)((char*)tab + A_N * sizeof(float4)); // 8*NPIX

    k1_kernel<<<dim3(2736), dim3(256), 0, stream>>>(
        sino, angles, w1, b1, w2, b2, sino_pred, inter, tab, part);
    bpb_kernel<<<dim3(24, 24, 4), dim3(256), 0, stream>>>(
        inter, tab, part);
    conv3_kernel<<<dim3(576), dim3(256), 0, stream>>>(
        part, w3, b3, img_sino, img_pred);
}

// Round 11
// 35.756 us; speedup vs baseline: 1.2421x; 1.2421x over previous
//
#include <hip/hip_runtime.h>

#define A_N 192
#define D_N 576
#define W_N 384
#define NPIX (W_N * W_N)   // 147456
#define NSIN (A_N * D_N)   // 110592
#define RSTR 580           // padded inter row stride (float2 units)

// ---- fused conv1+conv2 via on-demand boundary-class collapsed 9x9 kernels --
// conv2(conv1(x)) == 81-tap collapsed kernel on a zero-padded input tile,
// except for the conv2 q-mask [p+q in domain], which depends only on the
// pixel's edge-distance class. A tile only contains classes yc in [ylo,yhi],
// xc in [xlo,xhi] (interior blocks: exactly one), so compute only those.
// Writes inter[a*580+2+d] = (sino, sino_pred) interleaved (stride-580 rows,
// zero guard cells at d=-2,-1,576,577 so the backprojection needs no mask).
// Block 0 additionally fills the per-angle table tab[a]=(cb,sb,u,v) and the
// guard cells.
__global__ __launch_bounds__(256) void conv9_kernel(
    const float* __restrict__ sino, const float* __restrict__ angles,
    const float* __restrict__ w1, const float* __restrict__ b1,
    const float* __restrict__ w2, const float* __restrict__ b2,
    float* __restrict__ sino_pred, float2* __restrict__ inter,
    float4* __restrict__ tab)
{
    __shared__ float t[16][40];            // zero-padded 8x32 tile + 4 halo
    __shared__ float sw1[400], sw2[400], sb1[16];
    __shared__ float K[625], wsb1[25];
    __shared__ float Wcs[9][81];           // on-demand class kernels
    __shared__ float biasc[9];

    int tid = threadIdx.x;
    int byi = blockIdx.x / 18;             // 576/32 = 18 tiles in x
    int bxi = blockIdx.x % 18;
    int y0 = byi * 8, x0 = bxi * 32;

    if (blockIdx.x == 0) {                 // per-angle table + guard cells
        if (tid < A_N) {
            float s, c;
            sincosf(angles[tid], &s, &c);
            tab[tid] = make_float4(c, s, fmaf(576.f, c, -287.5f * s),
                                         fmaf(576.f, s,  287.5f * c));
        }
        for (int i = tid; i < A_N * 4; i += 256) {
            int a = i >> 2, j = i & 3;
            inter[a * RSTR + (j < 2 ? j : 576 + j)] = make_float2(0.f, 0.f);
        }
    }

    for (int i = tid; i < 640; i += 256) {
        int r = i / 40, c = i - r * 40;
        int gy = y0 - 4 + r, gx = x0 - 4 + c;
        t[r][c] = (gy >= 0 && gy < A_N && gx >= 0 && gx < D_N)
                ? sino[gy * D_N + gx] : 0.f;
    }
    for (int i = tid; i < 400; i += 256) { sw1[i] = w1[i]; sw2[i] = w2[i]; }
    if (tid < 16) sb1[tid] = b1[tid];
    __syncthreads();

    for (int i = tid; i < 625; i += 256) {
        int q = i / 25, r = i - q * 25;
        float acc = 0.f;
        #pragma unroll
        for (int c = 0; c < 16; ++c)
            acc = fmaf(sw2[c * 25 + q], sw1[c * 25 + r], acc);
        K[i] = acc;
    }
    if (tid < 25) {
        float acc = 0.f;
        #pragma unroll
        for (int c = 0; c < 16; ++c) acc = fmaf(sw2[c * 25 + tid], sb1[c], acc);
        wsb1[tid] = acc;
    }
    __syncthreads();

    int ylo = (y0 == 0) ? 0 : 2, yhi = (y0 == A_N - 8) ? 4 : 2;
    int xlo = (x0 == 0) ? 0 : 2, xhi = (x0 == D_N - 32) ? 4 : 2;
    int nx = xhi - xlo + 1;
    int nc = (yhi - ylo + 1) * nx;

    for (int e = tid; e < nc * 81; e += 256) {
        int ci = e / 81, s = e - ci * 81;
        int yc = ylo + ci / nx, xc = xlo + ci % nx;
        int sy = s / 9 - 4, sx = s % 9 - 4;
        float acc = 0.f;
        for (int qy = -2; qy <= 2; ++qy) {
            if ((yc == 0 && qy < 0) || (yc == 1 && qy < -1) ||
                (yc == 3 && qy > 1) || (yc == 4 && qy > 0)) continue;
            int vy = sy - qy; if (vy < -2 || vy > 2) continue;
            for (int qx = -2; qx <= 2; ++qx) {
                if ((xc == 0 && qx < 0) || (xc == 1 && qx < -1) ||
                    (xc == 3 && qx > 1) || (xc == 4 && qx > 0)) continue;
                int vx = sx - qx; if (vx < -2 || vx > 2) continue;
                acc += K[((qy + 2) * 5 + qx + 2) * 25 + (vy + 2) * 5 + (vx + 2)];
            }
        }
        Wcs[ci][s] = acc;
    }
    if (tid < nc) {
        int yc = ylo + tid / nx, xc = xlo + tid % nx;
        float acc = b2[0];
        for (int qy = -2; qy <= 2; ++qy) {
            if ((yc == 0 && qy < 0) || (yc == 1 && qy < -1) ||
                (yc == 3 && qy > 1) || (yc == 4 && qy > 0)) continue;
            for (int qx = -2; qx <= 2; ++qx) {
                if ((xc == 0 && qx < 0) || (xc == 1 && qx < -1) ||
                    (xc == 3 && qx > 1) || (xc == 4 && qx > 0)) continue;
                acc += wsb1[(qy + 2) * 5 + qx + 2];
            }
        }
        biasc[tid] = acc;
    }
    __syncthreads();

    int lr = tid >> 5, lc = tid & 31;
    int gy = y0 + lr, gx = x0 + lc;
    int yc = (gy <= 1) ? gy : ((gy >= A_N - 2) ? (gy - (A_N - 5)) : 2);
    int xc = (gx <= 1) ? gx : ((gx >= D_N - 2) ? (gx - (D_N - 5)) : 2);
    int ci = (yc - ylo) * nx + (xc - xlo);
    float acc = biasc[ci];
    const float* Wp = Wcs[ci];
    #pragma unroll
    for (int sy = 0; sy < 9; ++sy)
        #pragma unroll
        for (int sx = 0; sx < 9; ++sx)
            acc = fmaf(t[lr + sy][lc + sx], Wp[sy * 9 + sx], acc);
    sino_pred[gy * D_N + gx] = acc;
    inter[gy * RSTR + 2 + gx] = make_float2(t[lr + 4][lc + 4], acc);
}

// ---- dual fan-beam backprojection, 16x16 tiles, angle-split x4 -------------
// s = num/den, num = u*X + v*Y + 165600, den = 576 - sb*X + cb*Y (>= 304).
// Clamp in FLOAT: sc = med3(s, -2, 576). At the rails fr == 0 exactly or the
// taps read guard zeros (d=-2,-1,576,577), so weights need no masking at all.
// One clamped float4 gather covers both interp taps of both sinograms.
// unroll 8 -> 8 independent gathers in flight per thread.
// part layout: [img 0..3][img_sino 0..3] planes of NPIX.
__global__ __launch_bounds__(256) void backproject2_kernel(
    const float2* __restrict__ inter, const float4* __restrict__ tab,
    float* __restrict__ part)
{
    int tid = threadIdx.x;
    int seg = blockIdx.z;                  // 0..3
    int a0 = seg * 48;
    int tx = tid & 15, ty = tid >> 4;
    int gx = blockIdx.x * 16 + tx;
    int gy = blockIdx.y * 16 + ty;
    int idx = gy * W_N + gx;
    float X = (float)gx - 191.5f;
    float Y = (float)gy - 191.5f;
    float acc0 = 0.f, acc1 = 0.f;
    const float2* base = inter + (size_t)a0 * RSTR + 2;
    #pragma unroll 8
    for (int i = 0; i < 48; ++i) {
        float4 tb = tab[a0 + i];           // uniform -> scalar loads
        float den = fmaf(tb.x, Y, fmaf(-tb.y, X, 576.f));
        float num = fmaf(tb.z, X, fmaf(tb.w, Y, 165600.f));
        float s   = num * __builtin_amdgcn_rcpf(den);
        float sc  = fminf(fmaxf(s, -2.f), 576.f);   // v_med3_f32
        float fl  = floorf(sc);
        float fr  = sc - fl;
        int   ic  = (int)fl;
        float4 v = *reinterpret_cast<const float4*>(base + (size_t)i * RSTR + ic);
        acc0 = fmaf(v.x, 1.f - fr, fmaf(v.z, fr, acc0));
        acc1 = fmaf(v.y, 1.f - fr, fmaf(v.w, fr, acc1));
    }
    part[seg * NPIX + idx]       = acc0;
    part[(4 + seg) * NPIX + idx] = acc1;
}

// ---- fused partial-sum (x4) + conv3: writes img_sino and img_pred ----------
__global__ __launch_bounds__(256) void conv3_kernel(
    const float* __restrict__ part,
    const float* __restrict__ w3, const float* __restrict__ b3,
    float* __restrict__ img_sino, float* __restrict__ img_pred)
{
    __shared__ float t0[10][34], t1[10][34];
    __shared__ float sw[18];
    int tid = threadIdx.x;
    int byi = blockIdx.x / 12, bxi = blockIdx.x % 12;   // 384/32=12, 384/8=48
    int y0 = byi * 8, x0 = bxi * 32;
    for (int i = tid; i < 340; i += 256) {
        int r = i / 34, c = i - r * 34;
        int gy = y0 - 1 + r, gx = x0 - 1 + c;
        float s0 = 0.f, s1 = 0.f;
        if (gy >= 0 && gy < W_N && gx >= 0 && gx < W_N) {
            int g = gy * W_N + gx;
            #pragma unroll
            for (int p = 0; p < 4; ++p) s0 += part[p * NPIX + g];
            #pragma unroll
            for (int p = 4; p < 8; ++p) s1 += part[p * NPIX + g];
        }
        t0[r][c] = s0; t1[r][c] = s1;
    }
    if (tid < 18) sw[tid] = w3[tid];
    __syncthreads();
    int lr = tid >> 5, lc = tid & 31;
    int gy = y0 + lr, gx = x0 + lc;
    int g = gy * W_N + gx;
    img_sino[g] = t1[lr + 1][lc + 1];
    float acc = b3[0];
    #pragma unroll
    for (int dy = 0; dy < 3; ++dy)
        #pragma unroll
        for (int dx = 0; dx < 3; ++dx) {
            acc = fmaf(t0[lr + dy][lc + dx], sw[dy * 3 + dx], acc);
            acc = fmaf(t1[lr + dy][lc + dx], sw[9 + dy * 3 + dx], acc);
        }
    img_pred[g] = acc;
}

extern "C" void kernel_launch(void* const* d_in, const int* in_sizes, int n_in,
                              void* d_out, int out_size, void* d_ws, size_t ws_size,
                              hipStream_t stream) {
    const float* sino   = (const float*)d_in[0];
    const float* angles = (const float*)d_in[1];
    const float* w1     = (const float*)d_in[2];
    const float* b1     = (const float*)d_in[3];
    const float* w2     = (const float*)d_in[4];
    const float* b2     = (const float*)d_in[5];
    const float* w3     = (const float*)d_in[6];
    const float* b3     = (const float*)d_in[7];

    float* out       = (float*)d_out;
    float* sino_pred = out;                       // 110592
    float* img_sino  = out + NSIN;                // 147456
    float* img_pred  = img_sino + NPIX;           // 147456

    float2* inter = (float2*)d_ws;                          // 192*580 float2
    float4* tab   = (float4*)((char*)d_ws + (size_t)A_N * RSTR * sizeof(float2));
    float*  part  = (float*)((char*)tab + A_N * sizeof(float4)); // 8*NPIX

    conv9_kernel<<<dim3(432), dim3(256), 0, stream>>>(
        sino, angles, w1, b1, w2, b2, sino_pred, inter, tab);
    backproject2_kernel<<<dim3(24, 24, 4), dim3(256), 0, stream>>>(
        inter, tab, part);
    conv3_kernel<<<dim3(576), dim3(256), 0, stream>>>(
        part, w3, b3, img_sino, img_pred);
}

// Round 12
// 34.250 us; speedup vs baseline: 1.2967x; 1.0440x over previous
//
#include <hip/hip_runtime.h>

#define A_N 192
#define D_N 576
#define W_N 384
#define NPIX (W_N * W_N)   // 147456
#define NSIN (A_N * D_N)   // 110592
#define RSTR 580           // padded inter row stride (float2 units)

// ---- fused conv1+conv2 via on-demand boundary-class collapsed 9x9 kernels --
// conv2(conv1(x)) == 81-tap collapsed kernel on a zero-padded input tile,
// except for the conv2 q-mask [p+q in domain], which depends only on the
// pixel's edge-distance class. A tile only contains classes yc in [ylo,yhi],
// xc in [xlo,xhi] (interior blocks: exactly one), so compute only those.
// Writes inter[a*580+2+d] = (sino, sino_pred) interleaved (stride-580 rows,
// zero guard cells at d=-2,-1,576,577 so the backprojection needs no mask).
// Block 0 additionally fills the per-angle table tab[a]=(cb,sb,u,v) and the
// guard cells.
__global__ __launch_bounds__(256) void conv9_kernel(
    const float* __restrict__ sino, const float* __restrict__ angles,
    const float* __restrict__ w1, const float* __restrict__ b1,
    const float* __restrict__ w2, const float* __restrict__ b2,
    float* __restrict__ sino_pred, float2* __restrict__ inter,
    float4* __restrict__ tab)
{
    __shared__ float t[16][40];            // zero-padded 8x32 tile + 4 halo
    __shared__ float sw1[400], sw2[400], sb1[16];
    __shared__ float K[625], wsb1[25];
    __shared__ float Wcs[9][81];           // on-demand class kernels
    __shared__ float biasc[9];

    int tid = threadIdx.x;
    int byi = blockIdx.x / 18;             // 576/32 = 18 tiles in x
    int bxi = blockIdx.x % 18;
    int y0 = byi * 8, x0 = bxi * 32;

    if (blockIdx.x == 0) {                 // per-angle table + guard cells
        if (tid < A_N) {
            float s, c;
            sincosf(angles[tid], &s, &c);
            tab[tid] = make_float4(c, s, fmaf(576.f, c, -287.5f * s),
                                         fmaf(576.f, s,  287.5f * c));
        }
        for (int i = tid; i < A_N * 4; i += 256) {
            int a = i >> 2, j = i & 3;
            inter[a * RSTR + (j < 2 ? j : 576 + j)] = make_float2(0.f, 0.f);
        }
    }

    for (int i = tid; i < 640; i += 256) {
        int r = i / 40, c = i - r * 40;
        int gy = y0 - 4 + r, gx = x0 - 4 + c;
        t[r][c] = (gy >= 0 && gy < A_N && gx >= 0 && gx < D_N)
                ? sino[gy * D_N + gx] : 0.f;
    }
    for (int i = tid; i < 400; i += 256) { sw1[i] = w1[i]; sw2[i] = w2[i]; }
    if (tid < 16) sb1[tid] = b1[tid];
    __syncthreads();

    for (int i = tid; i < 625; i += 256) {
        int q = i / 25, r = i - q * 25;
        float acc = 0.f;
        #pragma unroll
        for (int c = 0; c < 16; ++c)
            acc = fmaf(sw2[c * 25 + q], sw1[c * 25 + r], acc);
        K[i] = acc;
    }
    if (tid < 25) {
        float acc = 0.f;
        #pragma unroll
        for (int c = 0; c < 16; ++c) acc = fmaf(sw2[c * 25 + tid], sb1[c], acc);
        wsb1[tid] = acc;
    }
    __syncthreads();

    int ylo = (y0 == 0) ? 0 : 2, yhi = (y0 == A_N - 8) ? 4 : 2;
    int xlo = (x0 == 0) ? 0 : 2, xhi = (x0 == D_N - 32) ? 4 : 2;
    int nx = xhi - xlo + 1;
    int nc = (yhi - ylo + 1) * nx;

    for (int e = tid; e < nc * 81; e += 256) {
        int ci = e / 81, s = e - ci * 81;
        int yc = ylo + ci / nx, xc = xlo + ci % nx;
        int sy = s / 9 - 4, sx = s % 9 - 4;
        float acc = 0.f;
        for (int qy = -2; qy <= 2; ++qy) {
            if ((yc == 0 && qy < 0) || (yc == 1 && qy < -1) ||
                (yc == 3 && qy > 1) || (yc == 4 && qy > 0)) continue;
            int vy = sy - qy; if (vy < -2 || vy > 2) continue;
            for (int qx = -2; qx <= 2; ++qx) {
                if ((xc == 0 && qx < 0) || (xc == 1 && qx < -1) ||
                    (xc == 3 && qx > 1) || (xc == 4 && qx > 0)) continue;
                int vx = sx - qx; if (vx < -2 || vx > 2) continue;
                acc += K[((qy + 2) * 5 + qx + 2) * 25 + (vy + 2) * 5 + (vx + 2)];
            }
        }
        Wcs[ci][s] = acc;
    }
    if (tid < nc) {
        int yc = ylo + tid / nx, xc = xlo + tid % nx;
        float acc = b2[0];
        for (int qy = -2; qy <= 2; ++qy) {
            if ((yc == 0 && qy < 0) || (yc == 1 && qy < -1) ||
                (yc == 3 && qy > 1) || (yc == 4 && qy > 0)) continue;
            for (int qx = -2; qx <= 2; ++qx) {
                if ((xc == 0 && qx < 0) || (xc == 1 && qx < -1) ||
                    (xc == 3 && qx > 1) || (xc == 4 && qx > 0)) continue;
                acc += wsb1[(qy + 2) * 5 + qx + 2];
            }
        }
        biasc[tid] = acc;
    }
    __syncthreads();

    int lr = tid >> 5, lc = tid & 31;
    int gy = y0 + lr, gx = x0 + lc;
    int yc = (gy <= 1) ? gy : ((gy >= A_N - 2) ? (gy - (A_N - 5)) : 2);
    int xc = (gx <= 1) ? gx : ((gx >= D_N - 2) ? (gx - (D_N - 5)) : 2);
    int ci = (yc - ylo) * nx + (xc - xlo);
    float acc = biasc[ci];
    const float* Wp = Wcs[ci];
    #pragma unroll
    for (int sy = 0; sy < 9; ++sy)
        #pragma unroll
        for (int sx = 0; sx < 9; ++sx)
            acc = fmaf(t[lr + sy][lc + sx], Wp[sy * 9 + sx], acc);
    sino_pred[gy * D_N + gx] = acc;
    inter[gy * RSTR + 2 + gx] = make_float2(t[lr + 4][lc + 4], acc);
}

// ---- dual fan-beam backprojection, 16x16 tiles, angle-split x3 -------------
// 1728 blocks of 4 waves = 6.75 blocks/CU -> entire grid co-resident in ONE
// scheduling batch (8-block/CU cap), no straggler batch.
// s = num/den; float clamp sc = med3(s,-2,576); guard zeros at d=-2,-1,576,
// 577 make out-of-range taps contribute 0 with no masking. One float4 gather
// covers both interp taps of both sinograms; unroll 8 for MLP.
// part2 layout: [seg][NPIX] float2 = (img, img_sino) partial sums.
__global__ __launch_bounds__(256) void backproject2_kernel(
    const float2* __restrict__ inter, const float4* __restrict__ tab,
    float2* __restrict__ part2)
{
    int tid = threadIdx.x;
    int seg = blockIdx.z;                  // 0..2
    int a0 = seg * 64;
    int tx = tid & 15, ty = tid >> 4;
    int gx = blockIdx.x * 16 + tx;
    int gy = blockIdx.y * 16 + ty;
    int idx = gy * W_N + gx;
    float X = (float)gx - 191.5f;
    float Y = (float)gy - 191.5f;
    float acc0 = 0.f, acc1 = 0.f;
    const float2* base = inter + (size_t)a0 * RSTR + 2;
    #pragma unroll 8
    for (int i = 0; i < 64; ++i) {
        float4 tb = tab[a0 + i];           // uniform -> scalar loads
        float den = fmaf(tb.x, Y, fmaf(-tb.y, X, 576.f));
        float num = fmaf(tb.z, X, fmaf(tb.w, Y, 165600.f));
        float s   = num * __builtin_amdgcn_rcpf(den);
        float sc  = fminf(fmaxf(s, -2.f), 576.f);   // v_med3_f32
        float fl  = floorf(sc);
        float fr  = sc - fl;
        int   ic  = (int)fl;
        float4 v = *reinterpret_cast<const float4*>(base + (size_t)i * RSTR + ic);
        acc0 = fmaf(v.x, 1.f - fr, fmaf(v.z, fr, acc0));
        acc1 = fmaf(v.y, 1.f - fr, fmaf(v.w, fr, acc1));
    }
    part2[seg * NPIX + idx] = make_float2(acc0, acc1);
}

// ---- fused partial-sum (x3) + conv3: writes img_sino and img_pred ----------
__global__ __launch_bounds__(256) void conv3_kernel(
    const float2* __restrict__ part2,
    const float* __restrict__ w3, const float* __restrict__ b3,
    float* __restrict__ img_sino, float* __restrict__ img_pred)
{
    __shared__ float t0[10][34], t1[10][34];
    __shared__ float sw[18];
    int tid = threadIdx.x;
    int byi = blockIdx.x / 12, bxi = blockIdx.x % 12;   // 384/32=12, 384/8=48
    int y0 = byi * 8, x0 = bxi * 32;
    for (int i = tid; i < 340; i += 256) {
        int r = i / 34, c = i - r * 34;
        int gy = y0 - 1 + r, gx = x0 - 1 + c;
        float s0 = 0.f, s1 = 0.f;
        if (gy >= 0 && gy < W_N && gx >= 0 && gx < W_N) {
            int g = gy * W_N + gx;
            #pragma unroll
            for (int p = 0; p < 3; ++p) {
                float2 v = part2[p * NPIX + g];
                s0 += v.x; s1 += v.y;
            }
        }
        t0[r][c] = s0; t1[r][c] = s1;
    }
    if (tid < 18) sw[tid] = w3[tid];
    __syncthreads();
    int lr = tid >> 5, lc = tid & 31;
    int gy = y0 + lr, gx = x0 + lc;
    int g = gy * W_N + gx;
    img_sino[g] = t1[lr + 1][lc + 1];
    float acc = b3[0];
    #pragma unroll
    for (int dy = 0; dy < 3; ++dy)
        #pragma unroll
        for (int dx = 0; dx < 3; ++dx) {
            acc = fmaf(t0[lr + dy][lc + dx], sw[dy * 3 + dx], acc);
            acc = fmaf(t1[lr + dy][lc + dx], sw[9 + dy * 3 + dx], acc);
        }
    img_pred[g] = acc;
}

extern "C" void kernel_launch(void* const* d_in, const int* in_sizes, int n_in,
                              void* d_out, int out_size, void* d_ws, size_t ws_size,
                              hipStream_t stream) {
    const float* sino   = (const float*)d_in[0];
    const float* angles = (const float*)d_in[1];
    const float* w1     = (const float*)d_in[2];
    const float* b1     = (const float*)d_in[3];
    const float* w2     = (const float*)d_in[4];
    const float* b2     = (const float*)d_in[5];
    const float* w3     = (const float*)d_in[6];
    const float* b3     = (const float*)d_in[7];

    float* out       = (float*)d_out;
    float* sino_pred = out;                       // 110592
    float* img_sino  = out + NSIN;                // 147456
    float* img_pred  = img_sino + NPIX;           // 147456

    float2* inter = (float2*)d_ws;                          // 192*580 float2
    float4* tab   = (float4*)((char*)d_ws + (size_t)A_N * RSTR * sizeof(float2));
    float2* part2 = (float2*)((char*)tab + A_N * sizeof(float4)); // 3*NPIX float2

    conv9_kernel<<<dim3(432), dim3(256), 0, stream>>>(
        sino, angles, w1, b1, w2, b2, sino_pred, inter, tab);
    backproject2_kernel<<<dim3(24, 24, 3), dim3(256), 0, stream>>>(
        inter, tab, part2);
    conv3_kernel<<<dim3(576), dim3(256), 0, stream>>>(
        part2, w3, b3, img_sino, img_pred);
}